// Round 11
// baseline (671.962 us; speedup 1.0000x reference)
//
#include <hip/hip_runtime.h>
#include <hip/hip_bf16.h>

// ---------------------------------------------------------------------------
// PIDMultiHeadAttention — Round 15.
// Round-14 post-mortem: glds16-B was correct (conflicts/fetch down, no spill)
// but SLOWER (202->225us): r13's B VALU overlapped load latency under MFMA;
// the DMA variant trades that for a barrier vmcnt-drain (guide §5 caveat).
// DMA lever closed on this 2-barrier structure.
// Round 15 = EXACT round-13 winner (544us) + two independent grafts:
//  1) __launch_bounds__(256,4) on mfma_gemm — gemm0 is latency-bound
//     (Occ 30%, VALU 53%, Mfma 16%): 4 blocks/CU adds TLP. VGPR 76<=128,
//     LDS 4x32KB<=160KB.
//  2) s_setprio(1) around attn MFMA clusters (T5: +4-7% on multi-wave attn).
// Sentinels: WRITE ~24.5MB, VGPR <= 128 (expect ~76), conflicts ~1.9e7.
// ---------------------------------------------------------------------------

#define D_MODEL 1024
#define T_SEQ   2048
#define B_SZ    2
#define M_ROWS  (B_SZ * T_SEQ)   // 4096
#define N_HEADS 16
#define D_HEAD  64

typedef unsigned short u16;
typedef unsigned int   u32;

typedef short  short8  __attribute__((ext_vector_type(8)));
typedef float  float4v __attribute__((ext_vector_type(4)));

__device__ __forceinline__ float bf2f(u16 u) {
    union { u32 i; float f; } c; c.i = ((u32)u) << 16; return c.f;
}
__device__ __forceinline__ u16 f2bf(float f) {
    union { float f; u32 i; } c; c.f = f;
    u32 i = c.i;
    i += 0x7FFFu + ((i >> 16) & 1u);   // RNE
    return (u16)(i >> 16);
}
__device__ __forceinline__ u16 f2bfc(float f) {
    __hip_bfloat16 h = __float2bfloat16(f);   // RNE; pairs to v_cvt_pk_bf16_f32
    union { __hip_bfloat16 h; u16 u; } c; c.h = h; return c.u;
}
__device__ __forceinline__ float ldin(const void* p, int i, int fl) {
    return fl ? ((const float*)p)[i] : bf2f(((const u16*)p)[i]);
}

// ---------------------------------------------------------------------------
// 0) wire-dtype detection (proven since round 2)
// ---------------------------------------------------------------------------
__global__ void detect_kernel(const u32* __restrict__ x, int* __restrict__ flag)
{
    if (threadIdx.x == 0 && blockIdx.x == 0) {
        int good = 0;
        for (int i = 0; i < 256; ++i) {
            union { u32 u; float f; } c; c.u = x[i];
            float a = fabsf(c.f);
            if (c.f == c.f && a > 1e-8f && a < 1e4f) ++good;
        }
        *flag = (good >= 192) ? 1 : 0;
    }
}

// ---------------------------------------------------------------------------
// 1) cumulative-mean scan (exact round-13 version)
// ---------------------------------------------------------------------------
__global__ __launch_bounds__(256) void scan_partial(
    const void* __restrict__ x, float* __restrict__ csum,
    const int* __restrict__ flagp)
{
    int fl = *flagp;
    int tid = blockIdx.x * 256 + threadIdx.x;   // 32768 = B * 16 * D
    int b = tid >> 14;
    int c = (tid >> 10) & 15;
    int d = tid & 1023;
    int base = (b * T_SEQ + c * 128) * D_MODEL + d;
    float s = 0.f;
#pragma unroll 8
    for (int t = 0; t < 128; ++t) s += ldin(x, base + t * D_MODEL, fl);
    csum[tid] = s;
}

__global__ __launch_bounds__(256) void scan_final(
    const void* __restrict__ x, const float* __restrict__ csum,
    u16* __restrict__ integ, const int* __restrict__ flagp)
{
    int fl = *flagp;
    int tid = blockIdx.x * 256 + threadIdx.x;
    int b = tid >> 14;
    int c = (tid >> 10) & 15;
    int d = tid & 1023;
    float pre = 0.f;
    int cbase = (b << 14) | d;
    for (int cc = 0; cc < c; ++cc) pre += csum[cbase + (cc << 10)];
    int base = (b * T_SEQ + c * 128) * D_MODEL + d;
    float run = pre;
    int t0 = c * 128;
    for (int t = 0; t < 128; ++t) {
        run += ldin(x, base + t * D_MODEL, fl);
        integ[base + t * D_MODEL] = f2bf(run / (float)(t0 + t + 1));
    }
}

// ---------------------------------------------------------------------------
// 2) gate softmax (unchanged, proven)
// ---------------------------------------------------------------------------
__global__ __launch_bounds__(64) void gates_kernel(
    const void* __restrict__ x,
    const void* __restrict__ qWg, const void* __restrict__ qbg,
    const void* __restrict__ kWg, const void* __restrict__ kbg,
    const void* __restrict__ vWg, const void* __restrict__ vbg,
    float* __restrict__ gq, float* __restrict__ gk, float* __restrict__ gv,
    const int* __restrict__ flagp)
{
    int fl = *flagp;
    int row = blockIdx.x;
    int l = threadIdx.x;
    int xb = row * D_MODEL;
    float p[9];
#pragma unroll
    for (int j = 0; j < 9; ++j) p[j] = 0.f;
#pragma unroll 4
    for (int i = 0; i < 16; ++i) {
        int d = l + 64 * i;
        float xv = ldin(x, xb + d, fl);
        p[0] += xv * ldin(qWg, d, fl);
        p[1] += xv * ldin(qWg, 1024 + d, fl);
        p[2] += xv * ldin(qWg, 2048 + d, fl);
        p[3] += xv * ldin(kWg, d, fl);
        p[4] += xv * ldin(kWg, 1024 + d, fl);
        p[5] += xv * ldin(kWg, 2048 + d, fl);
        p[6] += xv * ldin(vWg, d, fl);
        p[7] += xv * ldin(vWg, 1024 + d, fl);
        p[8] += xv * ldin(vWg, 2048 + d, fl);
    }
#pragma unroll
    for (int off = 32; off > 0; off >>= 1) {
#pragma unroll
        for (int j = 0; j < 9; ++j) p[j] += __shfl_down(p[j], off);
    }
    if (l == 0) {
        const void* bgs[3] = { qbg, kbg, vbg };
        float* outs[3] = { gq, gk, gv };
#pragma unroll
        for (int pr = 0; pr < 3; ++pr) {
            float a0 = p[pr * 3 + 0] + ldin(bgs[pr], 0, fl);
            float a1 = p[pr * 3 + 1] + ldin(bgs[pr], 1, fl);
            float a2 = p[pr * 3 + 2] + ldin(bgs[pr], 2, fl);
            float mx = fmaxf(a0, fmaxf(a1, a2));
            float e0 = __expf(a0 - mx), e1 = __expf(a1 - mx), e2 = __expf(a2 - mx);
            float inv = 1.f / (e0 + e1 + e2);
            outs[pr][row * 3 + 0] = e0 * inv;
            outs[pr][row * 3 + 1] = e1 * inv;
            outs[pr][row * 3 + 2] = e2 * inv;
        }
    }
}

// ---------------------------------------------------------------------------
// 2b) weight bf16 cache: convert (f32 wire) or copy (bf16 wire). Proven.
// ---------------------------------------------------------------------------
struct CvtArgs { const void* src[10]; };

__global__ __launch_bounds__(256) void cvt_w(
    CvtArgs a, u16* __restrict__ dst, const int* __restrict__ flagp)
{
    int fl = *flagp;
    int m = blockIdx.y;
    u16* d = dst + ((size_t)m << 20);
    int i = (blockIdx.x * 256 + threadIdx.x) * 8;
    if (fl) {
        const float* s = (const float*)a.src[m];
        float4 v0 = *(const float4*)(s + i);
        float4 v1 = *(const float4*)(s + i + 4);
        ushort4 o0, o1;
        o0.x = f2bfc(v0.x); o0.y = f2bfc(v0.y); o0.z = f2bfc(v0.z); o0.w = f2bfc(v0.w);
        o1.x = f2bfc(v1.x); o1.y = f2bfc(v1.y); o1.z = f2bfc(v1.z); o1.w = f2bfc(v1.w);
        *(ushort4*)(d + i) = o0;
        *(ushort4*)(d + i + 4) = o1;
    } else {
        const u16* s = (const u16*)a.src[m];
        *(ushort4*)(d + i)     = *(const ushort4*)(s + i);
        *(ushort4*)(d + i + 4) = *(const ushort4*)(s + i + 4);
    }
}

// ---------------------------------------------------------------------------
// 3) MFMA GEMM — exact round-13 body; only __launch_bounds__ 3 -> 4.
// ---------------------------------------------------------------------------
struct GemmArgs {
    const void* W[3][3];
    const float* G[3];
    u16* C[3];
};

template<int MODE, int BW16>
__global__ __launch_bounds__(256, 4) void mfma_gemm(
    const void* __restrict__ X, const u16* __restrict__ Ib,
    const u16* __restrict__ Abf, GemmArgs args,
    const void* __restrict__ bias, void* __restrict__ outp,
    const int* __restrict__ flagp, int Ktot)
{
    int fl = *flagp;
    __shared__ __align__(16) u16 As[2 * 4096];
    __shared__ __align__(16) u16 Bs[2 * 4096];

    int tid = threadIdx.x;
    int l = tid & 63, w = tid >> 6;
    int wm = w >> 1, wn = w & 1;
    int m0 = blockIdx.y * 128, n0 = blockIdx.x * 128;
    int z = blockIdx.z;
    int lane15 = l & 15, quad = l >> 4;
    int srow = tid >> 2;       // staging row 0..63
    int cs = tid & 3;          // k-chunk 0..3
    int skof = cs * 8;

    const void* W0; const void* W1; const void* W2;
    const float* G = nullptr;
    u16* Chead = nullptr;
    if (MODE == 0) {
        W0 = args.W[z][0]; W1 = args.W[z][1]; W2 = args.W[z][2];
        G = args.G[z]; Chead = args.C[z];
    } else {
        W0 = args.W[0][0]; W1 = W0; W2 = W0;
    }

    float gcoef[2][3];
    if (MODE == 0) {
#pragma unroll
        for (int c = 0; c < 2; ++c)
#pragma unroll
            for (int s = 0; s < 3; ++s)
                gcoef[c][s] = G[(m0 + c * 64 + srow) * 3 + s];
    }

    // prefetch registers (bf16 payload) — exact round-1 structure
    ushort4 ra[2][4];   // A: [c][cur0,cur1,prev0,prev1]
    ushort4 rb[2][2];   // B: [c][2]

    auto cvt4 = [](float4 t) {
        ushort4 u;
        u.x = f2bf(t.x); u.y = f2bf(t.y); u.z = f2bf(t.z); u.w = f2bf(t.w);
        return u;
    };
    auto ld8 = [&](const void* p, int idx, ushort4& o0, ushort4& o1) {
        if (fl) {
            o0 = cvt4(*(const float4*)((const float*)p + idx));
            o1 = cvt4(*(const float4*)((const float*)p + idx + 4));
        } else {
            o0 = *(const ushort4*)((const u16*)p + idx);
            o1 = *(const ushort4*)((const u16*)p + idx + 4);
        }
    };

    auto load_phase = [&](int k0) {
        int seg = k0 >> 10, ksrc = k0 & 1023;
        const void* Wse = (MODE == 0) ? (seg == 0 ? W0 : (seg == 1 ? W1 : W2)) : W0;
#pragma unroll
        for (int c = 0; c < 2; ++c) {
            int gm = m0 + c * 64 + srow;
            int idx = gm * 1024 + ksrc + skof;
            if (MODE == 1) {
                ra[c][0] = *(const ushort4*)&Abf[idx];
                ra[c][1] = *(const ushort4*)&Abf[idx + 4];
            } else if (seg == 1) {
                ra[c][0] = *(const ushort4*)&Ib[idx];
                ra[c][1] = *(const ushort4*)&Ib[idx + 4];
            } else {
                ld8(X, idx, ra[c][0], ra[c][1]);
                if (seg == 2 && (gm & (T_SEQ - 1)) != 0)
                    ld8(X, idx - 1024, ra[c][2], ra[c][3]);
            }
            int gn = n0 + c * 64 + srow;
            int bidx = gn * 1024 + ksrc + skof;
            if (BW16) {
                const u16* bs = (const u16*)Wse;
                rb[c][0] = *(const ushort4*)&bs[bidx];
                rb[c][1] = *(const ushort4*)&bs[bidx + 4];
            } else {
                ld8(Wse, bidx, rb[c][0], rb[c][1]);
            }
        }
    };

    auto unp8 = [](ushort4 a, ushort4 b, float v[8]) {
        v[0] = bf2f(a.x); v[1] = bf2f(a.y); v[2] = bf2f(a.z); v[3] = bf2f(a.w);
        v[4] = bf2f(b.x); v[5] = bf2f(b.y); v[6] = bf2f(b.z); v[7] = bf2f(b.w);
    };

    // precomputed swizzled write offsets (loop-invariant; proven round 10)
    int wo[2];
#pragma unroll
    for (int c = 0; c < 2; ++c) {
        int g = c * 16 + ((srow >> 4) << 2) + cs;
        wo[c] = (g << 7) | ((((srow & 15) + g) & 15) << 3);
    }

    auto store_phase = [&](int k0, int buf) {
        int seg = k0 >> 10;
        u16* Ad = As + buf * 4096;
        u16* Bd = Bs + buf * 4096;
#pragma unroll
        for (int c = 0; c < 2; ++c) {
            int row = c * 64 + srow;
            short8 pk;
            if (MODE == 1) {
                pk[0] = (short)ra[c][0].x; pk[1] = (short)ra[c][0].y;
                pk[2] = (short)ra[c][0].z; pk[3] = (short)ra[c][0].w;
                pk[4] = (short)ra[c][1].x; pk[5] = (short)ra[c][1].y;
                pk[6] = (short)ra[c][1].z; pk[7] = (short)ra[c][1].w;
            } else {
                float v[8];
                unp8(ra[c][0], ra[c][1], v);
                if (seg == 2) {
                    int gm = m0 + row;
                    if ((gm & (T_SEQ - 1)) == 0) {
#pragma unroll
                        for (int j = 0; j < 8; ++j) v[j] = 0.f;
                    } else {
                        float pv[8];
                        unp8(ra[c][2], ra[c][3], pv);
#pragma unroll
                        for (int j = 0; j < 8; ++j) v[j] -= pv[j];
                    }
                }
                float sc = gcoef[c][seg];
#pragma unroll
                for (int j = 0; j < 8; ++j) pk[j] = (short)f2bfc(v[j] * sc);
            }
            *(short8*)&Ad[wo[c]] = pk;

            short8 pb;
            pb[0] = (short)rb[c][0].x; pb[1] = (short)rb[c][0].y;
            pb[2] = (short)rb[c][0].z; pb[3] = (short)rb[c][0].w;
            pb[4] = (short)rb[c][1].x; pb[5] = (short)rb[c][1].y;
            pb[6] = (short)rb[c][1].z; pb[7] = (short)rb[c][1].w;
            *(short8*)&Bd[wo[c]] = pb;
        }
    };

    float4v acc[4][4];
#pragma unroll
    for (int i = 0; i < 4; ++i)
#pragma unroll
        for (int j = 0; j < 4; ++j)
#pragma unroll
            for (int r = 0; r < 4; ++r) acc[i][j][r] = 0.f;

    // precomputed swizzled read offsets (loop-invariant; proven round 10)
    int aro[4], bro[4];
#pragma unroll
    for (int t = 0; t < 4; ++t) {
        int ga = (wm * 4 + t) * 4 + quad;
        aro[t] = (ga << 7) | (((lane15 + ga) & 15) << 3);
        int gb = (wn * 4 + t) * 4 + quad;
        bro[t] = (gb << 7) | (((lane15 + gb) & 15) << 3);
    }

    int nIt = Ktot >> 5;
    load_phase(0);
    store_phase(0, 0);

    for (int it = 0; it < nIt; ++it) {
        __syncthreads();
        int cur = it & 1;
        if (it + 1 < nIt) load_phase((it + 1) << 5);

        short8 af[4], bfr[4];
#pragma unroll
        for (int ms = 0; ms < 4; ++ms)
            af[ms] = *(const short8*)&As[cur * 4096 + aro[ms]];
#pragma unroll
        for (int ns = 0; ns < 4; ++ns)
            bfr[ns] = *(const short8*)&Bs[cur * 4096 + bro[ns]];
#pragma unroll
        for (int ms = 0; ms < 4; ++ms)
#pragma unroll
            for (int ns = 0; ns < 4; ++ns)
                acc[ms][ns] = __builtin_amdgcn_mfma_f32_16x16x32_bf16(
                    af[ms], bfr[ns], acc[ms][ns], 0, 0, 0);

        if (it + 1 < nIt) store_phase((it + 1) << 5, 1 - cur);
    }

    // ---- epilogue (exact round-13) ----
#pragma unroll
    for (int ms = 0; ms < 4; ++ms) {
#pragma unroll
        for (int r = 0; r < 4; ++r) {
            int m = m0 + wm * 64 + ms * 16 + quad * 4 + r;
#pragma unroll
            for (int ns = 0; ns < 4; ++ns) {
                int n = n0 + wn * 64 + ns * 16 + lane15;
                float vv = acc[ms][ns][r];
                if (MODE == 0) {
                    int b = m >> 11, t = m & (T_SEQ - 1);
                    int h = n >> 6,  d = n & 63;
                    Chead[(((b << 4) + h) * T_SEQ + t) * 64 + d] = f2bf(vv);
                } else {
                    vv += ldin(bias, n, fl);
                    if (fl) ((float*)outp)[m * 1024 + n] = vv;
                    else    ((u16*)outp)[m * 1024 + n] = f2bf(vv);
                }
            }
        }
    }
}

// ---------------------------------------------------------------------------
// 4) MFMA flash attention — round-13 body + s_setprio around MFMA clusters
// ---------------------------------------------------------------------------
__global__ __launch_bounds__(256) void attn_mfma(
    const u16* __restrict__ Qh, const u16* __restrict__ Kh,
    const u16* __restrict__ Vh, u16* __restrict__ AO)
{
    int bx = blockIdx.x;          // 1024 = B*H*(T/64)
    int qt = bx & 31;
    int bh = bx >> 5;             // 0..31
    int h  = bh & 15;
    int b  = bh >> 4;
    int tid = threadIdx.x;
    int l   = tid & 63;
    int w   = tid >> 6;
    int lane15 = l & 15;
    int quad   = l >> 4;

    __shared__ __align__(16) u16 Ks[64 * 72];
    __shared__ __align__(16) u16 Vt[64 * 72];   // transposed: [d][t_local]
    __shared__ __align__(16) u16 Ps[4 * 16 * 72];

    const u16* Qb = Qh + bh * (T_SEQ * 64);
    const u16* Kb = Kh + bh * (T_SEQ * 64);
    const u16* Vb = Vh + bh * (T_SEQ * 64);

    int qrow = qt * 64 + w * 16 + lane15;
    short8 qf[2];
#pragma unroll
    for (int ks = 0; ks < 2; ++ks)
        qf[ks] = *(const short8*)&Qb[qrow * 64 + ks * 32 + quad * 8];

    float4v oacc[4];
#pragma unroll
    for (int ds = 0; ds < 4; ++ds)
#pragma unroll
        for (int r = 0; r < 4; ++r) oacc[ds][r] = 0.f;
    float mrun[4], lrun[4];
#pragma unroll
    for (int r = 0; r < 4; ++r) { mrun[r] = -1e30f; lrun[r] = 0.f; }

    int srow = tid >> 2;
    int sdc  = (tid & 3) * 16;

    for (int kt = 0; kt <= qt; ++kt) {
        {
            const u16* kp = &Kb[(kt * 64 + srow) * 64 + sdc];
            ushort4 a = *(const ushort4*)kp;
            ushort4 c = *(const ushort4*)(kp + 4);
            ushort4 d2 = *(const ushort4*)(kp + 8);
            ushort4 e = *(const ushort4*)(kp + 12);
            short8 p0, p1;
            p0[0]=a.x; p0[1]=a.y; p0[2]=a.z; p0[3]=a.w;
            p0[4]=c.x; p0[5]=c.y; p0[6]=c.z; p0[7]=c.w;
            p1[0]=d2.x; p1[1]=d2.y; p1[2]=d2.z; p1[3]=d2.w;
            p1[4]=e.x; p1[5]=e.y; p1[6]=e.z; p1[7]=e.w;
            *(short8*)&Ks[srow * 72 + sdc] = p0;
            *(short8*)&Ks[srow * 72 + sdc + 8] = p1;

            const u16* vp = &Vb[(kt * 64 + srow) * 64 + sdc];
            u16 vv[16];
            *(ushort4*)&vv[0]  = *(const ushort4*)vp;
            *(ushort4*)&vv[4]  = *(const ushort4*)(vp + 4);
            *(ushort4*)&vv[8]  = *(const ushort4*)(vp + 8);
            *(ushort4*)&vv[12] = *(const ushort4*)(vp + 12);
#pragma unroll
            for (int e2 = 0; e2 < 16; ++e2)
                Vt[(sdc + e2) * 72 + srow] = vv[e2];
        }
        __syncthreads();

        float4v sacc[4];
#pragma unroll
        for (int ns = 0; ns < 4; ++ns)
#pragma unroll
            for (int r = 0; r < 4; ++r) sacc[ns][r] = 0.f;
        __builtin_amdgcn_s_setprio(1);
#pragma unroll
        for (int ks = 0; ks < 2; ++ks) {
#pragma unroll
            for (int ns = 0; ns < 4; ++ns) {
                short8 bfk = *(const short8*)&Ks[(ns * 16 + lane15) * 72 + ks * 32 + quad * 8];
                sacc[ns] = __builtin_amdgcn_mfma_f32_16x16x32_bf16(
                    qf[ks], bfk, sacc[ns], 0, 0, 0);
            }
        }
        __builtin_amdgcn_s_setprio(0);

        int qg0 = qt * 64 + w * 16 + quad * 4;
#pragma unroll
        for (int ns = 0; ns < 4; ++ns) {
            int kg = kt * 64 + ns * 16 + lane15;
#pragma unroll
            for (int r = 0; r < 4; ++r) {
                float s = sacc[ns][r] * 0.125f;
                sacc[ns][r] = (kg > qg0 + r) ? -1e30f : s;
            }
        }
#pragma unroll
        for (int r = 0; r < 4; ++r) {
            float mx = fmaxf(fmaxf(sacc[0][r], sacc[1][r]),
                             fmaxf(sacc[2][r], sacc[3][r]));
#pragma unroll
            for (int m2 = 1; m2 < 16; m2 <<= 1)
                mx = fmaxf(mx, __shfl_xor(mx, m2, 64));
            float mnew = fmaxf(mrun[r], mx);
            float al = __expf(mrun[r] - mnew);
            float rs = 0.f;
#pragma unroll
            for (int ns = 0; ns < 4; ++ns) {
                float p = __expf(sacc[ns][r] - mnew);
                sacc[ns][r] = p;
                rs += p;
            }
#pragma unroll
            for (int m2 = 1; m2 < 16; m2 <<= 1)
                rs += __shfl_xor(rs, m2, 64);
            lrun[r] = lrun[r] * al + rs;
            mrun[r] = mnew;
#pragma unroll
            for (int ds = 0; ds < 4; ++ds) oacc[ds][r] *= al;
        }

        u16* Pw = &Ps[w * 16 * 72];
#pragma unroll
        for (int ns = 0; ns < 4; ++ns)
#pragma unroll
            for (int r = 0; r < 4; ++r)
                Pw[(quad * 4 + r) * 72 + ns * 16 + lane15] = f2bf(sacc[ns][r]);

        __builtin_amdgcn_s_setprio(1);
#pragma unroll
        for (int ks = 0; ks < 2; ++ks) {
            short8 afp = *(const short8*)&Pw[lane15 * 72 + ks * 32 + quad * 8];
#pragma unroll
            for (int ds = 0; ds < 4; ++ds) {
                short8 bfv = *(const short8*)&Vt[(ds * 16 + lane15) * 72 + ks * 32 + quad * 8];
                oacc[ds] = __builtin_amdgcn_mfma_f32_16x16x32_bf16(
                    afp, bfv, oacc[ds], 0, 0, 0);
            }
        }
        __builtin_amdgcn_s_setprio(0);
        __syncthreads();
    }

#pragma unroll
    for (int r = 0; r < 4; ++r) {
        float inv = 1.f / lrun[r];
        int t = qt * 64 + w * 16 + quad * 4 + r;
        int orow = (b * T_SEQ + t) * 1024 + h * 64;
#pragma unroll
        for (int ds = 0; ds < 4; ++ds)
            AO[orow + ds * 16 + lane15] = f2bf(oacc[ds][r] * inv);
    }
}

// ---------------------------------------------------------------------------
extern "C" void kernel_launch(void* const* d_in, const int* in_sizes, int n_in,
                              void* d_out, int out_size, void* d_ws, size_t ws_size,
                              hipStream_t stream)
{
    const void* x   = d_in[0];
    const void* qWp = d_in[1];
    const void* qWi = d_in[2];
    const void* qWd = d_in[3];
    const void* qWg = d_in[4];
    const void* qbg = d_in[5];
    const void* kWp = d_in[6];
    const void* kWi = d_in[7];
    const void* kWd = d_in[8];
    const void* kWg = d_in[9];
    const void* kbg = d_in[10];
    const void* vWp = d_in[11];
    const void* vWi = d_in[12];
    const void* vWd = d_in[13];
    const void* vWg = d_in[14];
    const void* vbg = d_in[15];
    const void* oW  = d_in[16];
    const void* ob  = d_in[17];

    const size_t SZ = (size_t)M_ROWS * D_MODEL;   // 4,194,304 elems

    // ws layout (base 33 MiB — proven):
    int*   flag = (int*)d_ws;
    float* fws  = (float*)d_ws;
    float* csum = fws + 64;
    float* gq   = csum + 32768;
    float* gk   = gq + 3 * M_ROWS;
    float* gv   = gk + 3 * M_ROWS;
    u16* Ib = (u16*)((char*)d_ws + (1u << 20));
    u16* AO = Ib;                  // alias, disjoint in time
    u16* Qh = Ib + SZ;
    u16* Kh = Qh + SZ;
    u16* Vh = Kh + SZ;

    // bf16 weight cache (proven: r12's 64-VGPR dispatch => ws_size >= 53MiB)
    const size_t NEED_FULL = (size_t)(1u << 20) + 4 * SZ * 2 + ((size_t)10 << 21);
    u16* wb = (ws_size >= NEED_FULL) ? (Vh + SZ) : nullptr;

    detect_kernel<<<1, 64, 0, stream>>>((const u32*)x, flag);
    scan_partial<<<128, 256, 0, stream>>>(x, csum, flag);
    scan_final<<<128, 256, 0, stream>>>(x, csum, Ib, flag);
    gates_kernel<<<M_ROWS, 64, 0, stream>>>(x, qWg, qbg, kWg, kbg, vWg, vbg,
                                            gq, gk, gv, flag);

    GemmArgs pa;
    pa.G[0] = gq; pa.G[1] = gk; pa.G[2] = gv;
    pa.C[0] = Qh; pa.C[1] = Kh; pa.C[2] = Vh;
    GemmArgs oa = {};

    if (wb) {
        CvtArgs ca;
        ca.src[0] = qWp; ca.src[1] = qWi; ca.src[2] = qWd;
        ca.src[3] = kWp; ca.src[4] = kWi; ca.src[5] = kWd;
        ca.src[6] = vWp; ca.src[7] = vWi; ca.src[8] = vWd;
        ca.src[9] = oW;
        cvt_w<<<dim3(512, 10), 256, 0, stream>>>(ca, wb, flag);

        for (int z2 = 0; z2 < 3; ++z2)
            for (int s2 = 0; s2 < 3; ++s2)
                pa.W[z2][s2] = wb + ((size_t)(z2 * 3 + s2) << 20);
        oa.W[0][0] = wb + ((size_t)9 << 20);

        mfma_gemm<0, 1><<<dim3(8, 32, 3), 256, 0, stream>>>(
            x, Ib, nullptr, pa, nullptr, nullptr, flag, 3072);
        attn_mfma<<<B_SZ * N_HEADS * (T_SEQ / 64), 256, 0, stream>>>(Qh, Kh, Vh, AO);
        mfma_gemm<1, 1><<<dim3(8, 32, 1), 256, 0, stream>>>(
            nullptr, nullptr, AO, oa, ob, d_out, flag, 1024);
    } else {
        pa.W[0][0] = qWp; pa.W[0][1] = qWi; pa.W[0][2] = qWd;
        pa.W[1][0] = kWp; pa.W[1][1] = kWi; pa.W[1][2] = kWd;
        pa.W[2][0] = vWp; pa.W[2][1] = vWi; pa.W[2][2] = vWd;
        oa.W[0][0] = oW;

        mfma_gemm<0, 0><<<dim3(8, 32, 3), 256, 0, stream>>>(
            x, Ib, nullptr, pa, nullptr, nullptr, flag, 3072);
        attn_mfma<<<B_SZ * N_HEADS * (T_SEQ / 64), 256, 0, stream>>>(Qh, Kh, Vh, AO);
        mfma_gemm<1, 0><<<dim3(8, 32, 1), 256, 0, stream>>>(
            nullptr, nullptr, AO, oa, ob, d_out, flag, 1024);
    }
}

// Round 12
// 529.134 us; speedup vs baseline: 1.2699x; 1.2699x over previous
//
#include <hip/hip_runtime.h>
#include <hip/hip_bf16.h>

// ---------------------------------------------------------------------------
// PIDMultiHeadAttention — Round 16.
// Round-15 post-mortem: launch_bounds(256,4) — gemm0 grid is 768 blocks =
// exactly 3/CU (GRID-limited occupancy); the bound only squeezed VGPR 76->64
// and caused mild spill (WRITE 43MB). setprio on attn ~neutral (lockstep
// 4-wave blocks = m190 null case, not m191). Both reverted.
// Round 16 = EXACT round-13 winner (544us) + two independent low-risk edits:
//  1) cvt4 (ld8's f32->bf16 for A seg0/seg2) f2bf -> f2bfc — the same
//     instruction-substitution class that won r13 (+18us, no spill).
//  2) XCD-aware bijective block swizzle: lin=bx+8*by; m=4*(lin&7)+(lin>>6),
//     n=(lin>>3)&7 — each XCD gets a contiguous 4-m-tile strip so A panels
//     are L2-local (FETCH 242MB vs 35MB logical today).
// Sentinels: WRITE ~24.5MB, VGPR ~76, conflicts ~1.9e7; FETCH = swizzle diag.
// ---------------------------------------------------------------------------

#define D_MODEL 1024
#define T_SEQ   2048
#define B_SZ    2
#define M_ROWS  (B_SZ * T_SEQ)   // 4096
#define N_HEADS 16
#define D_HEAD  64

typedef unsigned short u16;
typedef unsigned int   u32;

typedef short  short8  __attribute__((ext_vector_type(8)));
typedef float  float4v __attribute__((ext_vector_type(4)));

__device__ __forceinline__ float bf2f(u16 u) {
    union { u32 i; float f; } c; c.i = ((u32)u) << 16; return c.f;
}
__device__ __forceinline__ u16 f2bf(float f) {
    union { float f; u32 i; } c; c.f = f;
    u32 i = c.i;
    i += 0x7FFFu + ((i >> 16) & 1u);   // RNE
    return (u16)(i >> 16);
}
__device__ __forceinline__ u16 f2bfc(float f) {
    __hip_bfloat16 h = __float2bfloat16(f);   // RNE; pairs to v_cvt_pk_bf16_f32
    union { __hip_bfloat16 h; u16 u; } c; c.h = h; return c.u;
}
__device__ __forceinline__ float ldin(const void* p, int i, int fl) {
    return fl ? ((const float*)p)[i] : bf2f(((const u16*)p)[i]);
}

// ---------------------------------------------------------------------------
// 0) wire-dtype detection (proven since round 2)
// ---------------------------------------------------------------------------
__global__ void detect_kernel(const u32* __restrict__ x, int* __restrict__ flag)
{
    if (threadIdx.x == 0 && blockIdx.x == 0) {
        int good = 0;
        for (int i = 0; i < 256; ++i) {
            union { u32 u; float f; } c; c.u = x[i];
            float a = fabsf(c.f);
            if (c.f == c.f && a > 1e-8f && a < 1e4f) ++good;
        }
        *flag = (good >= 192) ? 1 : 0;
    }
}

// ---------------------------------------------------------------------------
// 1) cumulative-mean scan (exact round-13 version)
// ---------------------------------------------------------------------------
__global__ __launch_bounds__(256) void scan_partial(
    const void* __restrict__ x, float* __restrict__ csum,
    const int* __restrict__ flagp)
{
    int fl = *flagp;
    int tid = blockIdx.x * 256 + threadIdx.x;   // 32768 = B * 16 * D
    int b = tid >> 14;
    int c = (tid >> 10) & 15;
    int d = tid & 1023;
    int base = (b * T_SEQ + c * 128) * D_MODEL + d;
    float s = 0.f;
#pragma unroll 8
    for (int t = 0; t < 128; ++t) s += ldin(x, base + t * D_MODEL, fl);
    csum[tid] = s;
}

__global__ __launch_bounds__(256) void scan_final(
    const void* __restrict__ x, const float* __restrict__ csum,
    u16* __restrict__ integ, const int* __restrict__ flagp)
{
    int fl = *flagp;
    int tid = blockIdx.x * 256 + threadIdx.x;
    int b = tid >> 14;
    int c = (tid >> 10) & 15;
    int d = tid & 1023;
    float pre = 0.f;
    int cbase = (b << 14) | d;
    for (int cc = 0; cc < c; ++cc) pre += csum[cbase + (cc << 10)];
    int base = (b * T_SEQ + c * 128) * D_MODEL + d;
    float run = pre;
    int t0 = c * 128;
    for (int t = 0; t < 128; ++t) {
        run += ldin(x, base + t * D_MODEL, fl);
        integ[base + t * D_MODEL] = f2bf(run / (float)(t0 + t + 1));
    }
}

// ---------------------------------------------------------------------------
// 2) gate softmax (unchanged, proven)
// ---------------------------------------------------------------------------
__global__ __launch_bounds__(64) void gates_kernel(
    const void* __restrict__ x,
    const void* __restrict__ qWg, const void* __restrict__ qbg,
    const void* __restrict__ kWg, const void* __restrict__ kbg,
    const void* __restrict__ vWg, const void* __restrict__ vbg,
    float* __restrict__ gq, float* __restrict__ gk, float* __restrict__ gv,
    const int* __restrict__ flagp)
{
    int fl = *flagp;
    int row = blockIdx.x;
    int l = threadIdx.x;
    int xb = row * D_MODEL;
    float p[9];
#pragma unroll
    for (int j = 0; j < 9; ++j) p[j] = 0.f;
#pragma unroll 4
    for (int i = 0; i < 16; ++i) {
        int d = l + 64 * i;
        float xv = ldin(x, xb + d, fl);
        p[0] += xv * ldin(qWg, d, fl);
        p[1] += xv * ldin(qWg, 1024 + d, fl);
        p[2] += xv * ldin(qWg, 2048 + d, fl);
        p[3] += xv * ldin(kWg, d, fl);
        p[4] += xv * ldin(kWg, 1024 + d, fl);
        p[5] += xv * ldin(kWg, 2048 + d, fl);
        p[6] += xv * ldin(vWg, d, fl);
        p[7] += xv * ldin(vWg, 1024 + d, fl);
        p[8] += xv * ldin(vWg, 2048 + d, fl);
    }
#pragma unroll
    for (int off = 32; off > 0; off >>= 1) {
#pragma unroll
        for (int j = 0; j < 9; ++j) p[j] += __shfl_down(p[j], off);
    }
    if (l == 0) {
        const void* bgs[3] = { qbg, kbg, vbg };
        float* outs[3] = { gq, gk, gv };
#pragma unroll
        for (int pr = 0; pr < 3; ++pr) {
            float a0 = p[pr * 3 + 0] + ldin(bgs[pr], 0, fl);
            float a1 = p[pr * 3 + 1] + ldin(bgs[pr], 1, fl);
            float a2 = p[pr * 3 + 2] + ldin(bgs[pr], 2, fl);
            float mx = fmaxf(a0, fmaxf(a1, a2));
            float e0 = __expf(a0 - mx), e1 = __expf(a1 - mx), e2 = __expf(a2 - mx);
            float inv = 1.f / (e0 + e1 + e2);
            outs[pr][row * 3 + 0] = e0 * inv;
            outs[pr][row * 3 + 1] = e1 * inv;
            outs[pr][row * 3 + 2] = e2 * inv;
        }
    }
}

// ---------------------------------------------------------------------------
// 2b) weight bf16 cache: convert (f32 wire) or copy (bf16 wire). Proven.
// ---------------------------------------------------------------------------
struct CvtArgs { const void* src[10]; };

__global__ __launch_bounds__(256) void cvt_w(
    CvtArgs a, u16* __restrict__ dst, const int* __restrict__ flagp)
{
    int fl = *flagp;
    int m = blockIdx.y;
    u16* d = dst + ((size_t)m << 20);
    int i = (blockIdx.x * 256 + threadIdx.x) * 8;
    if (fl) {
        const float* s = (const float*)a.src[m];
        float4 v0 = *(const float4*)(s + i);
        float4 v1 = *(const float4*)(s + i + 4);
        ushort4 o0, o1;
        o0.x = f2bfc(v0.x); o0.y = f2bfc(v0.y); o0.z = f2bfc(v0.z); o0.w = f2bfc(v0.w);
        o1.x = f2bfc(v1.x); o1.y = f2bfc(v1.y); o1.z = f2bfc(v1.z); o1.w = f2bfc(v1.w);
        *(ushort4*)(d + i) = o0;
        *(ushort4*)(d + i + 4) = o1;
    } else {
        const u16* s = (const u16*)a.src[m];
        *(ushort4*)(d + i)     = *(const ushort4*)(s + i);
        *(ushort4*)(d + i + 4) = *(const ushort4*)(s + i + 4);
    }
}

// ---------------------------------------------------------------------------
// 3) MFMA GEMM — exact round-13 body with two edits:
//    (a) cvt4 uses f2bfc (cvt_pk) — r13's proven substitution, second site
//    (b) XCD-aware bijective (bx,by)->(m,n) swizzle
// ---------------------------------------------------------------------------
struct GemmArgs {
    const void* W[3][3];
    const float* G[3];
    u16* C[3];
};

template<int MODE, int BW16>
__global__ __launch_bounds__(256, 3) void mfma_gemm(
    const void* __restrict__ X, const u16* __restrict__ Ib,
    const u16* __restrict__ Abf, GemmArgs args,
    const void* __restrict__ bias, void* __restrict__ outp,
    const int* __restrict__ flagp, int Ktot)
{
    int fl = *flagp;
    __shared__ __align__(16) u16 As[2 * 4096];
    __shared__ __align__(16) u16 Bs[2 * 4096];

    int tid = threadIdx.x;
    int l = tid & 63, w = tid >> 6;
    int wm = w >> 1, wn = w & 1;
    // XCD-aware swizzle: lin in [0,256); XCD = lin&7 (round-robin assumption).
    // m = 4*(lin&7) + (lin>>6), n = (lin>>3)&7  — bijective; each XCD works a
    // contiguous 4-m-tile strip so A panels stay L2-local.
    int lin = blockIdx.x + (blockIdx.y << 3);
    int m0 = ((((lin & 7) << 2) + (lin >> 6))) * 128;
    int n0 = ((lin >> 3) & 7) * 128;
    int z = blockIdx.z;
    int lane15 = l & 15, quad = l >> 4;
    int srow = tid >> 2;       // staging row 0..63
    int cs = tid & 3;          // k-chunk 0..3
    int skof = cs * 8;

    const void* W0; const void* W1; const void* W2;
    const float* G = nullptr;
    u16* Chead = nullptr;
    if (MODE == 0) {
        W0 = args.W[z][0]; W1 = args.W[z][1]; W2 = args.W[z][2];
        G = args.G[z]; Chead = args.C[z];
    } else {
        W0 = args.W[0][0]; W1 = W0; W2 = W0;
    }

    float gcoef[2][3];
    if (MODE == 0) {
#pragma unroll
        for (int c = 0; c < 2; ++c)
#pragma unroll
            for (int s = 0; s < 3; ++s)
                gcoef[c][s] = G[(m0 + c * 64 + srow) * 3 + s];
    }

    // prefetch registers (bf16 payload) — exact round-1 structure
    ushort4 ra[2][4];   // A: [c][cur0,cur1,prev0,prev1]
    ushort4 rb[2][2];   // B: [c][2]

    auto cvt4 = [](float4 t) {
        ushort4 u;
        u.x = f2bfc(t.x); u.y = f2bfc(t.y); u.z = f2bfc(t.z); u.w = f2bfc(t.w);
        return u;
    };
    auto ld8 = [&](const void* p, int idx, ushort4& o0, ushort4& o1) {
        if (fl) {
            o0 = cvt4(*(const float4*)((const float*)p + idx));
            o1 = cvt4(*(const float4*)((const float*)p + idx + 4));
        } else {
            o0 = *(const ushort4*)((const u16*)p + idx);
            o1 = *(const ushort4*)((const u16*)p + idx + 4);
        }
    };

    auto load_phase = [&](int k0) {
        int seg = k0 >> 10, ksrc = k0 & 1023;
        const void* Wse = (MODE == 0) ? (seg == 0 ? W0 : (seg == 1 ? W1 : W2)) : W0;
#pragma unroll
        for (int c = 0; c < 2; ++c) {
            int gm = m0 + c * 64 + srow;
            int idx = gm * 1024 + ksrc + skof;
            if (MODE == 1) {
                ra[c][0] = *(const ushort4*)&Abf[idx];
                ra[c][1] = *(const ushort4*)&Abf[idx + 4];
            } else if (seg == 1) {
                ra[c][0] = *(const ushort4*)&Ib[idx];
                ra[c][1] = *(const ushort4*)&Ib[idx + 4];
            } else {
                ld8(X, idx, ra[c][0], ra[c][1]);
                if (seg == 2 && (gm & (T_SEQ - 1)) != 0)
                    ld8(X, idx - 1024, ra[c][2], ra[c][3]);
            }
            int gn = n0 + c * 64 + srow;
            int bidx = gn * 1024 + ksrc + skof;
            if (BW16) {
                const u16* bs = (const u16*)Wse;
                rb[c][0] = *(const ushort4*)&bs[bidx];
                rb[c][1] = *(const ushort4*)&bs[bidx + 4];
            } else {
                ld8(Wse, bidx, rb[c][0], rb[c][1]);
            }
        }
    };

    auto unp8 = [](ushort4 a, ushort4 b, float v[8]) {
        v[0] = bf2f(a.x); v[1] = bf2f(a.y); v[2] = bf2f(a.z); v[3] = bf2f(a.w);
        v[4] = bf2f(b.x); v[5] = bf2f(b.y); v[6] = bf2f(b.z); v[7] = bf2f(b.w);
    };

    // precomputed swizzled write offsets (loop-invariant; proven round 10)
    int wo[2];
#pragma unroll
    for (int c = 0; c < 2; ++c) {
        int g = c * 16 + ((srow >> 4) << 2) + cs;
        wo[c] = (g << 7) | ((((srow & 15) + g) & 15) << 3);
    }

    auto store_phase = [&](int k0, int buf) {
        int seg = k0 >> 10;
        u16* Ad = As + buf * 4096;
        u16* Bd = Bs + buf * 4096;
#pragma unroll
        for (int c = 0; c < 2; ++c) {
            int row = c * 64 + srow;
            short8 pk;
            if (MODE == 1) {
                pk[0] = (short)ra[c][0].x; pk[1] = (short)ra[c][0].y;
                pk[2] = (short)ra[c][0].z; pk[3] = (short)ra[c][0].w;
                pk[4] = (short)ra[c][1].x; pk[5] = (short)ra[c][1].y;
                pk[6] = (short)ra[c][1].z; pk[7] = (short)ra[c][1].w;
            } else {
                float v[8];
                unp8(ra[c][0], ra[c][1], v);
                if (seg == 2) {
                    int gm = m0 + row;
                    if ((gm & (T_SEQ - 1)) == 0) {
#pragma unroll
                        for (int j = 0; j < 8; ++j) v[j] = 0.f;
                    } else {
                        float pv[8];
                        unp8(ra[c][2], ra[c][3], pv);
#pragma unroll
                        for (int j = 0; j < 8; ++j) v[j] -= pv[j];
                    }
                }
                float sc = gcoef[c][seg];
#pragma unroll
                for (int j = 0; j < 8; ++j) pk[j] = (short)f2bfc(v[j] * sc);
            }
            *(short8*)&Ad[wo[c]] = pk;

            short8 pb;
            pb[0] = (short)rb[c][0].x; pb[1] = (short)rb[c][0].y;
            pb[2] = (short)rb[c][0].z; pb[3] = (short)rb[c][0].w;
            pb[4] = (short)rb[c][1].x; pb[5] = (short)rb[c][1].y;
            pb[6] = (short)rb[c][1].z; pb[7] = (short)rb[c][1].w;
            *(short8*)&Bd[wo[c]] = pb;
        }
    };

    float4v acc[4][4];
#pragma unroll
    for (int i = 0; i < 4; ++i)
#pragma unroll
        for (int j = 0; j < 4; ++j)
#pragma unroll
            for (int r = 0; r < 4; ++r) acc[i][j][r] = 0.f;

    // precomputed swizzled read offsets (loop-invariant; proven round 10)
    int aro[4], bro[4];
#pragma unroll
    for (int t = 0; t < 4; ++t) {
        int ga = (wm * 4 + t) * 4 + quad;
        aro[t] = (ga << 7) | (((lane15 + ga) & 15) << 3);
        int gb = (wn * 4 + t) * 4 + quad;
        bro[t] = (gb << 7) | (((lane15 + gb) & 15) << 3);
    }

    int nIt = Ktot >> 5;
    load_phase(0);
    store_phase(0, 0);

    for (int it = 0; it < nIt; ++it) {
        __syncthreads();
        int cur = it & 1;
        if (it + 1 < nIt) load_phase((it + 1) << 5);

        short8 af[4], bfr[4];
#pragma unroll
        for (int ms = 0; ms < 4; ++ms)
            af[ms] = *(const short8*)&As[cur * 4096 + aro[ms]];
#pragma unroll
        for (int ns = 0; ns < 4; ++ns)
            bfr[ns] = *(const short8*)&Bs[cur * 4096 + bro[ns]];
#pragma unroll
        for (int ms = 0; ms < 4; ++ms)
#pragma unroll
            for (int ns = 0; ns < 4; ++ns)
                acc[ms][ns] = __builtin_amdgcn_mfma_f32_16x16x32_bf16(
                    af[ms], bfr[ns], acc[ms][ns], 0, 0, 0);

        if (it + 1 < nIt) store_phase((it + 1) << 5, 1 - cur);
    }

    // ---- epilogue (exact round-13) ----
#pragma unroll
    for (int ms = 0; ms < 4; ++ms) {
#pragma unroll
        for (int r = 0; r < 4; ++r) {
            int m = m0 + wm * 64 + ms * 16 + quad * 4 + r;
#pragma unroll
            for (int ns = 0; ns < 4; ++ns) {
                int n = n0 + wn * 64 + ns * 16 + lane15;
                float vv = acc[ms][ns][r];
                if (MODE == 0) {
                    int b = m >> 11, t = m & (T_SEQ - 1);
                    int h = n >> 6,  d = n & 63;
                    Chead[(((b << 4) + h) * T_SEQ + t) * 64 + d] = f2bf(vv);
                } else {
                    vv += ldin(bias, n, fl);
                    if (fl) ((float*)outp)[m * 1024 + n] = vv;
                    else    ((u16*)outp)[m * 1024 + n] = f2bf(vv);
                }
            }
        }
    }
}

// ---------------------------------------------------------------------------
// 4) MFMA flash attention (exact round-13 — proven, no setprio)
// ---------------------------------------------------------------------------
__global__ __launch_bounds__(256) void attn_mfma(
    const u16* __restrict__ Qh, const u16* __restrict__ Kh,
    const u16* __restrict__ Vh, u16* __restrict__ AO)
{
    int bx = blockIdx.x;          // 1024 = B*H*(T/64)
    int qt = bx & 31;
    int bh = bx >> 5;             // 0..31
    int h  = bh & 15;
    int b  = bh >> 4;
    int tid = threadIdx.x;
    int l   = tid & 63;
    int w   = tid >> 6;
    int lane15 = l & 15;
    int quad   = l >> 4;

    __shared__ __align__(16) u16 Ks[64 * 72];
    __shared__ __align__(16) u16 Vt[64 * 72];   // transposed: [d][t_local]
    __shared__ __align__(16) u16 Ps[4 * 16 * 72];

    const u16* Qb = Qh + bh * (T_SEQ * 64);
    const u16* Kb = Kh + bh * (T_SEQ * 64);
    const u16* Vb = Vh + bh * (T_SEQ * 64);

    int qrow = qt * 64 + w * 16 + lane15;
    short8 qf[2];
#pragma unroll
    for (int ks = 0; ks < 2; ++ks)
        qf[ks] = *(const short8*)&Qb[qrow * 64 + ks * 32 + quad * 8];

    float4v oacc[4];
#pragma unroll
    for (int ds = 0; ds < 4; ++ds)
#pragma unroll
        for (int r = 0; r < 4; ++r) oacc[ds][r] = 0.f;
    float mrun[4], lrun[4];
#pragma unroll
    for (int r = 0; r < 4; ++r) { mrun[r] = -1e30f; lrun[r] = 0.f; }

    int srow = tid >> 2;
    int sdc  = (tid & 3) * 16;

    for (int kt = 0; kt <= qt; ++kt) {
        {
            const u16* kp = &Kb[(kt * 64 + srow) * 64 + sdc];
            ushort4 a = *(const ushort4*)kp;
            ushort4 c = *(const ushort4*)(kp + 4);
            ushort4 d2 = *(const ushort4*)(kp + 8);
            ushort4 e = *(const ushort4*)(kp + 12);
            short8 p0, p1;
            p0[0]=a.x; p0[1]=a.y; p0[2]=a.z; p0[3]=a.w;
            p0[4]=c.x; p0[5]=c.y; p0[6]=c.z; p0[7]=c.w;
            p1[0]=d2.x; p1[1]=d2.y; p1[2]=d2.z; p1[3]=d2.w;
            p1[4]=e.x; p1[5]=e.y; p1[6]=e.z; p1[7]=e.w;
            *(short8*)&Ks[srow * 72 + sdc] = p0;
            *(short8*)&Ks[srow * 72 + sdc + 8] = p1;

            const u16* vp = &Vb[(kt * 64 + srow) * 64 + sdc];
            u16 vv[16];
            *(ushort4*)&vv[0]  = *(const ushort4*)vp;
            *(ushort4*)&vv[4]  = *(const ushort4*)(vp + 4);
            *(ushort4*)&vv[8]  = *(const ushort4*)(vp + 8);
            *(ushort4*)&vv[12] = *(const ushort4*)(vp + 12);
#pragma unroll
            for (int e2 = 0; e2 < 16; ++e2)
                Vt[(sdc + e2) * 72 + srow] = vv[e2];
        }
        __syncthreads();

        float4v sacc[4];
#pragma unroll
        for (int ns = 0; ns < 4; ++ns)
#pragma unroll
            for (int r = 0; r < 4; ++r) sacc[ns][r] = 0.f;
#pragma unroll
        for (int ks = 0; ks < 2; ++ks) {
#pragma unroll
            for (int ns = 0; ns < 4; ++ns) {
                short8 bfk = *(const short8*)&Ks[(ns * 16 + lane15) * 72 + ks * 32 + quad * 8];
                sacc[ns] = __builtin_amdgcn_mfma_f32_16x16x32_bf16(
                    qf[ks], bfk, sacc[ns], 0, 0, 0);
            }
        }

        int qg0 = qt * 64 + w * 16 + quad * 4;
#pragma unroll
        for (int ns = 0; ns < 4; ++ns) {
            int kg = kt * 64 + ns * 16 + lane15;
#pragma unroll
            for (int r = 0; r < 4; ++r) {
                float s = sacc[ns][r] * 0.125f;
                sacc[ns][r] = (kg > qg0 + r) ? -1e30f : s;
            }
        }
#pragma unroll
        for (int r = 0; r < 4; ++r) {
            float mx = fmaxf(fmaxf(sacc[0][r], sacc[1][r]),
                             fmaxf(sacc[2][r], sacc[3][r]));
#pragma unroll
            for (int m2 = 1; m2 < 16; m2 <<= 1)
                mx = fmaxf(mx, __shfl_xor(mx, m2, 64));
            float mnew = fmaxf(mrun[r], mx);
            float al = __expf(mrun[r] - mnew);
            float rs = 0.f;
#pragma unroll
            for (int ns = 0; ns < 4; ++ns) {
                float p = __expf(sacc[ns][r] - mnew);
                sacc[ns][r] = p;
                rs += p;
            }
#pragma unroll
            for (int m2 = 1; m2 < 16; m2 <<= 1)
                rs += __shfl_xor(rs, m2, 64);
            lrun[r] = lrun[r] * al + rs;
            mrun[r] = mnew;
#pragma unroll
            for (int ds = 0; ds < 4; ++ds) oacc[ds][r] *= al;
        }

        u16* Pw = &Ps[w * 16 * 72];
#pragma unroll
        for (int ns = 0; ns < 4; ++ns)
#pragma unroll
            for (int r = 0; r < 4; ++r)
                Pw[(quad * 4 + r) * 72 + ns * 16 + lane15] = f2bf(sacc[ns][r]);

#pragma unroll
        for (int ks = 0; ks < 2; ++ks) {
            short8 afp = *(const short8*)&Pw[lane15 * 72 + ks * 32 + quad * 8];
#pragma unroll
            for (int ds = 0; ds < 4; ++ds) {
                short8 bfv = *(const short8*)&Vt[(ds * 16 + lane15) * 72 + ks * 32 + quad * 8];
                oacc[ds] = __builtin_amdgcn_mfma_f32_16x16x32_bf16(
                    afp, bfv, oacc[ds], 0, 0, 0);
            }
        }
        __syncthreads();
    }

#pragma unroll
    for (int r = 0; r < 4; ++r) {
        float inv = 1.f / lrun[r];
        int t = qt * 64 + w * 16 + quad * 4 + r;
        int orow = (b * T_SEQ + t) * 1024 + h * 64;
#pragma unroll
        for (int ds = 0; ds < 4; ++ds)
            AO[orow + ds * 16 + lane15] = f2bf(oacc[ds][r] * inv);
    }
}

// ---------------------------------------------------------------------------
extern "C" void kernel_launch(void* const* d_in, const int* in_sizes, int n_in,
                              void* d_out, int out_size, void* d_ws, size_t ws_size,
                              hipStream_t stream)
{
    const void* x   = d_in[0];
    const void* qWp = d_in[1];
    const void* qWi = d_in[2];
    const void* qWd = d_in[3];
    const void* qWg = d_in[4];
    const void* qbg = d_in[5];
    const void* kWp = d_in[6];
    const void* kWi = d_in[7];
    const void* kWd = d_in[8];
    const void* kWg = d_in[9];
    const void* kbg = d_in[10];
    const void* vWp = d_in[11];
    const void* vWi = d_in[12];
    const void* vWd = d_in[13];
    const void* vWg = d_in[14];
    const void* vbg = d_in[15];
    const void* oW  = d_in[16];
    const void* ob  = d_in[17];

    const size_t SZ = (size_t)M_ROWS * D_MODEL;   // 4,194,304 elems

    // ws layout (base 33 MiB — proven):
    int*   flag = (int*)d_ws;
    float* fws  = (float*)d_ws;
    float* csum = fws + 64;
    float* gq   = csum + 32768;
    float* gk   = gq + 3 * M_ROWS;
    float* gv   = gk + 3 * M_ROWS;
    u16* Ib = (u16*)((char*)d_ws + (1u << 20));
    u16* AO = Ib;                  // alias, disjoint in time
    u16* Qh = Ib + SZ;
    u16* Kh = Qh + SZ;
    u16* Vh = Kh + SZ;

    // bf16 weight cache (proven: r12's 64-VGPR dispatch => ws_size >= 53MiB)
    const size_t NEED_FULL = (size_t)(1u << 20) + 4 * SZ * 2 + ((size_t)10 << 21);
    u16* wb = (ws_size >= NEED_FULL) ? (Vh + SZ) : nullptr;

    detect_kernel<<<1, 64, 0, stream>>>((const u32*)x, flag);
    scan_partial<<<128, 256, 0, stream>>>(x, csum, flag);
    scan_final<<<128, 256, 0, stream>>>(x, csum, Ib, flag);
    gates_kernel<<<M_ROWS, 64, 0, stream>>>(x, qWg, qbg, kWg, kbg, vWg, vbg,
                                            gq, gk, gv, flag);

    GemmArgs pa;
    pa.G[0] = gq; pa.G[1] = gk; pa.G[2] = gv;
    pa.C[0] = Qh; pa.C[1] = Kh; pa.C[2] = Vh;
    GemmArgs oa = {};

    if (wb) {
        CvtArgs ca;
        ca.src[0] = qWp; ca.src[1] = qWi; ca.src[2] = qWd;
        ca.src[3] = kWp; ca.src[4] = kWi; ca.src[5] = kWd;
        ca.src[6] = vWp; ca.src[7] = vWi; ca.src[8] = vWd;
        ca.src[9] = oW;
        cvt_w<<<dim3(512, 10), 256, 0, stream>>>(ca, wb, flag);

        for (int z2 = 0; z2 < 3; ++z2)
            for (int s2 = 0; s2 < 3; ++s2)
                pa.W[z2][s2] = wb + ((size_t)(z2 * 3 + s2) << 20);
        oa.W[0][0] = wb + ((size_t)9 << 20);

        mfma_gemm<0, 1><<<dim3(8, 32, 3), 256, 0, stream>>>(
            x, Ib, nullptr, pa, nullptr, nullptr, flag, 3072);
        attn_mfma<<<B_SZ * N_HEADS * (T_SEQ / 64), 256, 0, stream>>>(Qh, Kh, Vh, AO);
        mfma_gemm<1, 1><<<dim3(8, 32, 1), 256, 0, stream>>>(
            nullptr, nullptr, AO, oa, ob, d_out, flag, 1024);
    } else {
        pa.W[0][0] = qWp; pa.W[0][1] = qWi; pa.W[0][2] = qWd;
        pa.W[1][0] = kWp; pa.W[1][1] = kWi; pa.W[1][2] = kWd;
        pa.W[2][0] = vWp; pa.W[2][1] = vWi; pa.W[2][2] = vWd;
        oa.W[0][0] = oW;

        mfma_gemm<0, 0><<<dim3(8, 32, 3), 256, 0, stream>>>(
            x, Ib, nullptr, pa, nullptr, nullptr, flag, 3072);
        attn_mfma<<<B_SZ * N_HEADS * (T_SEQ / 64), 256, 0, stream>>>(Qh, Kh, Vh, AO);
        mfma_gemm<1, 0><<<dim3(8, 32, 1), 256, 0, stream>>>(
            nullptr, nullptr, AO, oa, ob, d_out, flag, 1024);
    }
}

// Round 13
// 490.757 us; speedup vs baseline: 1.3692x; 1.0782x over previous
//
#include <hip/hip_runtime.h>
#include <hip/hip_bf16.h>

// ---------------------------------------------------------------------------
// PIDMultiHeadAttention — Round 17.
// Round-16 won (544->529us): XCD swizzle (FETCH 242->96MB) + cvt4 f2bfc.
// gemm0 now 189us @ VALUBusy 55% — A-staging-bound; seg2's derivative chain
// (double x fetch, 16 bf2f, 8 subs per iter) is the biggest staging cost.
// Round 17 = EXACT round-16 winner + ONE edit:
//  * scan_final re-emits bf16 derivative db -> d_out scratch (r11-proven
//    code path; d_out dead until gemm1, stream-ordered safe, 8MiB both wires)
//  * gemm0 seg2 branch = byte-mirror of the proven seg1/Ib branch
//    (passthrough load from Abf=db); store_phase seg2 special case deleted;
//    ra shrinks [2][4]->[2][2] (register pressure DOWN)
// Sentinels: WRITE ~24.5MB, VGPR <= 76 (expect ~72), conflicts ~1.9e7.
// ---------------------------------------------------------------------------

#define D_MODEL 1024
#define T_SEQ   2048
#define B_SZ    2
#define M_ROWS  (B_SZ * T_SEQ)   // 4096
#define N_HEADS 16
#define D_HEAD  64

typedef unsigned short u16;
typedef unsigned int   u32;

typedef short  short8  __attribute__((ext_vector_type(8)));
typedef float  float4v __attribute__((ext_vector_type(4)));

__device__ __forceinline__ float bf2f(u16 u) {
    union { u32 i; float f; } c; c.i = ((u32)u) << 16; return c.f;
}
__device__ __forceinline__ u16 f2bf(float f) {
    union { float f; u32 i; } c; c.f = f;
    u32 i = c.i;
    i += 0x7FFFu + ((i >> 16) & 1u);   // RNE
    return (u16)(i >> 16);
}
__device__ __forceinline__ u16 f2bfc(float f) {
    __hip_bfloat16 h = __float2bfloat16(f);   // RNE; pairs to v_cvt_pk_bf16_f32
    union { __hip_bfloat16 h; u16 u; } c; c.h = h; return c.u;
}
__device__ __forceinline__ float ldin(const void* p, int i, int fl) {
    return fl ? ((const float*)p)[i] : bf2f(((const u16*)p)[i]);
}

// ---------------------------------------------------------------------------
// 0) wire-dtype detection (proven since round 2)
// ---------------------------------------------------------------------------
__global__ void detect_kernel(const u32* __restrict__ x, int* __restrict__ flag)
{
    if (threadIdx.x == 0 && blockIdx.x == 0) {
        int good = 0;
        for (int i = 0; i < 256; ++i) {
            union { u32 u; float f; } c; c.u = x[i];
            float a = fabsf(c.f);
            if (c.f == c.f && a > 1e-8f && a < 1e4f) ++good;
        }
        *flag = (good >= 192) ? 1 : 0;
    }
}

// ---------------------------------------------------------------------------
// 1) cumulative-mean scan; scan_final also emits the bf16 derivative into
//    d_out scratch (r11-proven pattern, xb omitted)
// ---------------------------------------------------------------------------
__global__ __launch_bounds__(256) void scan_partial(
    const void* __restrict__ x, float* __restrict__ csum,
    const int* __restrict__ flagp)
{
    int fl = *flagp;
    int tid = blockIdx.x * 256 + threadIdx.x;   // 32768 = B * 16 * D
    int b = tid >> 14;
    int c = (tid >> 10) & 15;
    int d = tid & 1023;
    int base = (b * T_SEQ + c * 128) * D_MODEL + d;
    float s = 0.f;
#pragma unroll 8
    for (int t = 0; t < 128; ++t) s += ldin(x, base + t * D_MODEL, fl);
    csum[tid] = s;
}

__global__ __launch_bounds__(256) void scan_final(
    const void* __restrict__ x, const float* __restrict__ csum,
    u16* __restrict__ integ, u16* __restrict__ db,
    const int* __restrict__ flagp)
{
    int fl = *flagp;
    int tid = blockIdx.x * 256 + threadIdx.x;
    int b = tid >> 14;
    int c = (tid >> 10) & 15;
    int d = tid & 1023;
    float pre = 0.f;
    int cbase = (b << 14) | d;
    for (int cc = 0; cc < c; ++cc) pre += csum[cbase + (cc << 10)];
    int base = (b * T_SEQ + c * 128) * D_MODEL + d;
    float run = pre;
    int t0 = c * 128;
    float xprev = (c != 0) ? ldin(x, base - D_MODEL, fl) : 0.f;
    for (int t = 0; t < 128; ++t) {
        float xv = ldin(x, base + t * D_MODEL, fl);
        run += xv;
        integ[base + t * D_MODEL] = f2bf(run / (float)(t0 + t + 1));
        float dv = (t0 + t == 0) ? 0.f : (xv - xprev);
        db[base + t * D_MODEL] = f2bf(dv);
        xprev = xv;
    }
}

// ---------------------------------------------------------------------------
// 2) gate softmax (unchanged, proven)
// ---------------------------------------------------------------------------
__global__ __launch_bounds__(64) void gates_kernel(
    const void* __restrict__ x,
    const void* __restrict__ qWg, const void* __restrict__ qbg,
    const void* __restrict__ kWg, const void* __restrict__ kbg,
    const void* __restrict__ vWg, const void* __restrict__ vbg,
    float* __restrict__ gq, float* __restrict__ gk, float* __restrict__ gv,
    const int* __restrict__ flagp)
{
    int fl = *flagp;
    int row = blockIdx.x;
    int l = threadIdx.x;
    int xb = row * D_MODEL;
    float p[9];
#pragma unroll
    for (int j = 0; j < 9; ++j) p[j] = 0.f;
#pragma unroll 4
    for (int i = 0; i < 16; ++i) {
        int d = l + 64 * i;
        float xv = ldin(x, xb + d, fl);
        p[0] += xv * ldin(qWg, d, fl);
        p[1] += xv * ldin(qWg, 1024 + d, fl);
        p[2] += xv * ldin(qWg, 2048 + d, fl);
        p[3] += xv * ldin(kWg, d, fl);
        p[4] += xv * ldin(kWg, 1024 + d, fl);
        p[5] += xv * ldin(kWg, 2048 + d, fl);
        p[6] += xv * ldin(vWg, d, fl);
        p[7] += xv * ldin(vWg, 1024 + d, fl);
        p[8] += xv * ldin(vWg, 2048 + d, fl);
    }
#pragma unroll
    for (int off = 32; off > 0; off >>= 1) {
#pragma unroll
        for (int j = 0; j < 9; ++j) p[j] += __shfl_down(p[j], off);
    }
    if (l == 0) {
        const void* bgs[3] = { qbg, kbg, vbg };
        float* outs[3] = { gq, gk, gv };
#pragma unroll
        for (int pr = 0; pr < 3; ++pr) {
            float a0 = p[pr * 3 + 0] + ldin(bgs[pr], 0, fl);
            float a1 = p[pr * 3 + 1] + ldin(bgs[pr], 1, fl);
            float a2 = p[pr * 3 + 2] + ldin(bgs[pr], 2, fl);
            float mx = fmaxf(a0, fmaxf(a1, a2));
            float e0 = __expf(a0 - mx), e1 = __expf(a1 - mx), e2 = __expf(a2 - mx);
            float inv = 1.f / (e0 + e1 + e2);
            outs[pr][row * 3 + 0] = e0 * inv;
            outs[pr][row * 3 + 1] = e1 * inv;
            outs[pr][row * 3 + 2] = e2 * inv;
        }
    }
}

// ---------------------------------------------------------------------------
// 2b) weight bf16 cache: convert (f32 wire) or copy (bf16 wire). Proven.
// ---------------------------------------------------------------------------
struct CvtArgs { const void* src[10]; };

__global__ __launch_bounds__(256) void cvt_w(
    CvtArgs a, u16* __restrict__ dst, const int* __restrict__ flagp)
{
    int fl = *flagp;
    int m = blockIdx.y;
    u16* d = dst + ((size_t)m << 20);
    int i = (blockIdx.x * 256 + threadIdx.x) * 8;
    if (fl) {
        const float* s = (const float*)a.src[m];
        float4 v0 = *(const float4*)(s + i);
        float4 v1 = *(const float4*)(s + i + 4);
        ushort4 o0, o1;
        o0.x = f2bfc(v0.x); o0.y = f2bfc(v0.y); o0.z = f2bfc(v0.z); o0.w = f2bfc(v0.w);
        o1.x = f2bfc(v1.x); o1.y = f2bfc(v1.y); o1.z = f2bfc(v1.z); o1.w = f2bfc(v1.w);
        *(ushort4*)(d + i) = o0;
        *(ushort4*)(d + i + 4) = o1;
    } else {
        const u16* s = (const u16*)a.src[m];
        *(ushort4*)(d + i)     = *(const ushort4*)(s + i);
        *(ushort4*)(d + i + 4) = *(const ushort4*)(s + i + 4);
    }
}

// ---------------------------------------------------------------------------
// 3) MFMA GEMM — round-16 body with ONE edit: seg2 loads the precomputed
//    bf16 derivative from Abf (mirror of the seg1/Ib branch); store_phase
//    seg2 special case deleted (ra shrinks to [2][2]).
// ---------------------------------------------------------------------------
struct GemmArgs {
    const void* W[3][3];
    const float* G[3];
    u16* C[3];
};

template<int MODE, int BW16>
__global__ __launch_bounds__(256, 3) void mfma_gemm(
    const void* __restrict__ X, const u16* __restrict__ Ib,
    const u16* __restrict__ Abf, GemmArgs args,
    const void* __restrict__ bias, void* __restrict__ outp,
    const int* __restrict__ flagp, int Ktot)
{
    int fl = *flagp;
    __shared__ __align__(16) u16 As[2 * 4096];
    __shared__ __align__(16) u16 Bs[2 * 4096];

    int tid = threadIdx.x;
    int l = tid & 63, w = tid >> 6;
    int wm = w >> 1, wn = w & 1;
    // XCD-aware swizzle (proven round 16: FETCH 242->96MB)
    int lin = blockIdx.x + (blockIdx.y << 3);
    int m0 = ((((lin & 7) << 2) + (lin >> 6))) * 128;
    int n0 = ((lin >> 3) & 7) * 128;
    int z = blockIdx.z;
    int lane15 = l & 15, quad = l >> 4;
    int srow = tid >> 2;       // staging row 0..63
    int cs = tid & 3;          // k-chunk 0..3
    int skof = cs * 8;

    const void* W0; const void* W1; const void* W2;
    const float* G = nullptr;
    u16* Chead = nullptr;
    if (MODE == 0) {
        W0 = args.W[z][0]; W1 = args.W[z][1]; W2 = args.W[z][2];
        G = args.G[z]; Chead = args.C[z];
    } else {
        W0 = args.W[0][0]; W1 = W0; W2 = W0;
    }

    float gcoef[2][3];
    if (MODE == 0) {
#pragma unroll
        for (int c = 0; c < 2; ++c)
#pragma unroll
            for (int s = 0; s < 3; ++s)
                gcoef[c][s] = G[(m0 + c * 64 + srow) * 3 + s];
    }

    // prefetch registers (bf16 payload)
    ushort4 ra[2][2];   // A: [c][2]
    ushort4 rb[2][2];   // B: [c][2]

    auto cvt4 = [](float4 t) {
        ushort4 u;
        u.x = f2bfc(t.x); u.y = f2bfc(t.y); u.z = f2bfc(t.z); u.w = f2bfc(t.w);
        return u;
    };
    auto ld8 = [&](const void* p, int idx, ushort4& o0, ushort4& o1) {
        if (fl) {
            o0 = cvt4(*(const float4*)((const float*)p + idx));
            o1 = cvt4(*(const float4*)((const float*)p + idx + 4));
        } else {
            o0 = *(const ushort4*)((const u16*)p + idx);
            o1 = *(const ushort4*)((const u16*)p + idx + 4);
        }
    };

    auto load_phase = [&](int k0) {
        int seg = k0 >> 10, ksrc = k0 & 1023;
        const void* Wse = (MODE == 0) ? (seg == 0 ? W0 : (seg == 1 ? W1 : W2)) : W0;
#pragma unroll
        for (int c = 0; c < 2; ++c) {
            int gm = m0 + c * 64 + srow;
            int idx = gm * 1024 + ksrc + skof;
            if (MODE == 1) {
                ra[c][0] = *(const ushort4*)&Abf[idx];
                ra[c][1] = *(const ushort4*)&Abf[idx + 4];
            } else if (seg == 1) {
                ra[c][0] = *(const ushort4*)&Ib[idx];
                ra[c][1] = *(const ushort4*)&Ib[idx + 4];
            } else if (seg == 2) {
                ra[c][0] = *(const ushort4*)&Abf[idx];
                ra[c][1] = *(const ushort4*)&Abf[idx + 4];
            } else {
                ld8(X, idx, ra[c][0], ra[c][1]);
            }
            int gn = n0 + c * 64 + srow;
            int bidx = gn * 1024 + ksrc + skof;
            if (BW16) {
                const u16* bs = (const u16*)Wse;
                rb[c][0] = *(const ushort4*)&bs[bidx];
                rb[c][1] = *(const ushort4*)&bs[bidx + 4];
            } else {
                ld8(Wse, bidx, rb[c][0], rb[c][1]);
            }
        }
    };

    auto unp8 = [](ushort4 a, ushort4 b, float v[8]) {
        v[0] = bf2f(a.x); v[1] = bf2f(a.y); v[2] = bf2f(a.z); v[3] = bf2f(a.w);
        v[4] = bf2f(b.x); v[5] = bf2f(b.y); v[6] = bf2f(b.z); v[7] = bf2f(b.w);
    };

    // precomputed swizzled write offsets (loop-invariant; proven round 10)
    int wo[2];
#pragma unroll
    for (int c = 0; c < 2; ++c) {
        int g = c * 16 + ((srow >> 4) << 2) + cs;
        wo[c] = (g << 7) | ((((srow & 15) + g) & 15) << 3);
    }

    auto store_phase = [&](int k0, int buf) {
        int seg = k0 >> 10;
        u16* Ad = As + buf * 4096;
        u16* Bd = Bs + buf * 4096;
#pragma unroll
        for (int c = 0; c < 2; ++c) {
            short8 pk;
            if (MODE == 1) {
                pk[0] = (short)ra[c][0].x; pk[1] = (short)ra[c][0].y;
                pk[2] = (short)ra[c][0].z; pk[3] = (short)ra[c][0].w;
                pk[4] = (short)ra[c][1].x; pk[5] = (short)ra[c][1].y;
                pk[6] = (short)ra[c][1].z; pk[7] = (short)ra[c][1].w;
            } else {
                float v[8];
                unp8(ra[c][0], ra[c][1], v);
                float sc = gcoef[c][seg];
#pragma unroll
                for (int j = 0; j < 8; ++j) pk[j] = (short)f2bfc(v[j] * sc);
            }
            *(short8*)&Ad[wo[c]] = pk;

            short8 pb;
            pb[0] = (short)rb[c][0].x; pb[1] = (short)rb[c][0].y;
            pb[2] = (short)rb[c][0].z; pb[3] = (short)rb[c][0].w;
            pb[4] = (short)rb[c][1].x; pb[5] = (short)rb[c][1].y;
            pb[6] = (short)rb[c][1].z; pb[7] = (short)rb[c][1].w;
            *(short8*)&Bd[wo[c]] = pb;
        }
    };

    float4v acc[4][4];
#pragma unroll
    for (int i = 0; i < 4; ++i)
#pragma unroll
        for (int j = 0; j < 4; ++j)
#pragma unroll
            for (int r = 0; r < 4; ++r) acc[i][j][r] = 0.f;

    // precomputed swizzled read offsets (loop-invariant; proven round 10)
    int aro[4], bro[4];
#pragma unroll
    for (int t = 0; t < 4; ++t) {
        int ga = (wm * 4 + t) * 4 + quad;
        aro[t] = (ga << 7) | (((lane15 + ga) & 15) << 3);
        int gb = (wn * 4 + t) * 4 + quad;
        bro[t] = (gb << 7) | (((lane15 + gb) & 15) << 3);
    }

    int nIt = Ktot >> 5;
    load_phase(0);
    store_phase(0, 0);

    for (int it = 0; it < nIt; ++it) {
        __syncthreads();
        int cur = it & 1;
        if (it + 1 < nIt) load_phase((it + 1) << 5);

        short8 af[4], bfr[4];
#pragma unroll
        for (int ms = 0; ms < 4; ++ms)
            af[ms] = *(const short8*)&As[cur * 4096 + aro[ms]];
#pragma unroll
        for (int ns = 0; ns < 4; ++ns)
            bfr[ns] = *(const short8*)&Bs[cur * 4096 + bro[ns]];
#pragma unroll
        for (int ms = 0; ms < 4; ++ms)
#pragma unroll
            for (int ns = 0; ns < 4; ++ns)
                acc[ms][ns] = __builtin_amdgcn_mfma_f32_16x16x32_bf16(
                    af[ms], bfr[ns], acc[ms][ns], 0, 0, 0);

        if (it + 1 < nIt) store_phase((it + 1) << 5, 1 - cur);
    }

    // ---- epilogue (exact round-16) ----
#pragma unroll
    for (int ms = 0; ms < 4; ++ms) {
#pragma unroll
        for (int r = 0; r < 4; ++r) {
            int m = m0 + wm * 64 + ms * 16 + quad * 4 + r;
#pragma unroll
            for (int ns = 0; ns < 4; ++ns) {
                int n = n0 + wn * 64 + ns * 16 + lane15;
                float vv = acc[ms][ns][r];
                if (MODE == 0) {
                    int b = m >> 11, t = m & (T_SEQ - 1);
                    int h = n >> 6,  d = n & 63;
                    Chead[(((b << 4) + h) * T_SEQ + t) * 64 + d] = f2bf(vv);
                } else {
                    vv += ldin(bias, n, fl);
                    if (fl) ((float*)outp)[m * 1024 + n] = vv;
                    else    ((u16*)outp)[m * 1024 + n] = f2bf(vv);
                }
            }
        }
    }
}

// ---------------------------------------------------------------------------
// 4) MFMA flash attention (exact round-13 — proven)
// ---------------------------------------------------------------------------
__global__ __launch_bounds__(256) void attn_mfma(
    const u16* __restrict__ Qh, const u16* __restrict__ Kh,
    const u16* __restrict__ Vh, u16* __restrict__ AO)
{
    int bx = blockIdx.x;          // 1024 = B*H*(T/64)
    int qt = bx & 31;
    int bh = bx >> 5;             // 0..31
    int h  = bh & 15;
    int b  = bh >> 4;
    int tid = threadIdx.x;
    int l   = tid & 63;
    int w   = tid >> 6;
    int lane15 = l & 15;
    int quad   = l >> 4;

    __shared__ __align__(16) u16 Ks[64 * 72];
    __shared__ __align__(16) u16 Vt[64 * 72];   // transposed: [d][t_local]
    __shared__ __align__(16) u16 Ps[4 * 16 * 72];

    const u16* Qb = Qh + bh * (T_SEQ * 64);
    const u16* Kb = Kh + bh * (T_SEQ * 64);
    const u16* Vb = Vh + bh * (T_SEQ * 64);

    int qrow = qt * 64 + w * 16 + lane15;
    short8 qf[2];
#pragma unroll
    for (int ks = 0; ks < 2; ++ks)
        qf[ks] = *(const short8*)&Qb[qrow * 64 + ks * 32 + quad * 8];

    float4v oacc[4];
#pragma unroll
    for (int ds = 0; ds < 4; ++ds)
#pragma unroll
        for (int r = 0; r < 4; ++r) oacc[ds][r] = 0.f;
    float mrun[4], lrun[4];
#pragma unroll
    for (int r = 0; r < 4; ++r) { mrun[r] = -1e30f; lrun[r] = 0.f; }

    int srow = tid >> 2;
    int sdc  = (tid & 3) * 16;

    for (int kt = 0; kt <= qt; ++kt) {
        {
            const u16* kp = &Kb[(kt * 64 + srow) * 64 + sdc];
            ushort4 a = *(const ushort4*)kp;
            ushort4 c = *(const ushort4*)(kp + 4);
            ushort4 d2 = *(const ushort4*)(kp + 8);
            ushort4 e = *(const ushort4*)(kp + 12);
            short8 p0, p1;
            p0[0]=a.x; p0[1]=a.y; p0[2]=a.z; p0[3]=a.w;
            p0[4]=c.x; p0[5]=c.y; p0[6]=c.z; p0[7]=c.w;
            p1[0]=d2.x; p1[1]=d2.y; p1[2]=d2.z; p1[3]=d2.w;
            p1[4]=e.x; p1[5]=e.y; p1[6]=e.z; p1[7]=e.w;
            *(short8*)&Ks[srow * 72 + sdc] = p0;
            *(short8*)&Ks[srow * 72 + sdc + 8] = p1;

            const u16* vp = &Vb[(kt * 64 + srow) * 64 + sdc];
            u16 vv[16];
            *(ushort4*)&vv[0]  = *(const ushort4*)vp;
            *(ushort4*)&vv[4]  = *(const ushort4*)(vp + 4);
            *(ushort4*)&vv[8]  = *(const ushort4*)(vp + 8);
            *(ushort4*)&vv[12] = *(const ushort4*)(vp + 12);
#pragma unroll
            for (int e2 = 0; e2 < 16; ++e2)
                Vt[(sdc + e2) * 72 + srow] = vv[e2];
        }
        __syncthreads();

        float4v sacc[4];
#pragma unroll
        for (int ns = 0; ns < 4; ++ns)
#pragma unroll
            for (int r = 0; r < 4; ++r) sacc[ns][r] = 0.f;
#pragma unroll
        for (int ks = 0; ks < 2; ++ks) {
#pragma unroll
            for (int ns = 0; ns < 4; ++ns) {
                short8 bfk = *(const short8*)&Ks[(ns * 16 + lane15) * 72 + ks * 32 + quad * 8];
                sacc[ns] = __builtin_amdgcn_mfma_f32_16x16x32_bf16(
                    qf[ks], bfk, sacc[ns], 0, 0, 0);
            }
        }

        int qg0 = qt * 64 + w * 16 + quad * 4;
#pragma unroll
        for (int ns = 0; ns < 4; ++ns) {
            int kg = kt * 64 + ns * 16 + lane15;
#pragma unroll
            for (int r = 0; r < 4; ++r) {
                float s = sacc[ns][r] * 0.125f;
                sacc[ns][r] = (kg > qg0 + r) ? -1e30f : s;
            }
        }
#pragma unroll
        for (int r = 0; r < 4; ++r) {
            float mx = fmaxf(fmaxf(sacc[0][r], sacc[1][r]),
                             fmaxf(sacc[2][r], sacc[3][r]));
#pragma unroll
            for (int m2 = 1; m2 < 16; m2 <<= 1)
                mx = fmaxf(mx, __shfl_xor(mx, m2, 64));
            float mnew = fmaxf(mrun[r], mx);
            float al = __expf(mrun[r] - mnew);
            float rs = 0.f;
#pragma unroll
            for (int ns = 0; ns < 4; ++ns) {
                float p = __expf(sacc[ns][r] - mnew);
                sacc[ns][r] = p;
                rs += p;
            }
#pragma unroll
            for (int m2 = 1; m2 < 16; m2 <<= 1)
                rs += __shfl_xor(rs, m2, 64);
            lrun[r] = lrun[r] * al + rs;
            mrun[r] = mnew;
#pragma unroll
            for (int ds = 0; ds < 4; ++ds) oacc[ds][r] *= al;
        }

        u16* Pw = &Ps[w * 16 * 72];
#pragma unroll
        for (int ns = 0; ns < 4; ++ns)
#pragma unroll
            for (int r = 0; r < 4; ++r)
                Pw[(quad * 4 + r) * 72 + ns * 16 + lane15] = f2bf(sacc[ns][r]);

#pragma unroll
        for (int ks = 0; ks < 2; ++ks) {
            short8 afp = *(const short8*)&Pw[lane15 * 72 + ks * 32 + quad * 8];
#pragma unroll
            for (int ds = 0; ds < 4; ++ds) {
                short8 bfv = *(const short8*)&Vt[(ds * 16 + lane15) * 72 + ks * 32 + quad * 8];
                oacc[ds] = __builtin_amdgcn_mfma_f32_16x16x32_bf16(
                    afp, bfv, oacc[ds], 0, 0, 0);
            }
        }
        __syncthreads();
    }

#pragma unroll
    for (int r = 0; r < 4; ++r) {
        float inv = 1.f / lrun[r];
        int t = qt * 64 + w * 16 + quad * 4 + r;
        int orow = (b * T_SEQ + t) * 1024 + h * 64;
#pragma unroll
        for (int ds = 0; ds < 4; ++ds)
            AO[orow + ds * 16 + lane15] = f2bf(oacc[ds][r] * inv);
    }
}

// ---------------------------------------------------------------------------
extern "C" void kernel_launch(void* const* d_in, const int* in_sizes, int n_in,
                              void* d_out, int out_size, void* d_ws, size_t ws_size,
                              hipStream_t stream)
{
    const void* x   = d_in[0];
    const void* qWp = d_in[1];
    const void* qWi = d_in[2];
    const void* qWd = d_in[3];
    const void* qWg = d_in[4];
    const void* qbg = d_in[5];
    const void* kWp = d_in[6];
    const void* kWi = d_in[7];
    const void* kWd = d_in[8];
    const void* kWg = d_in[9];
    const void* kbg = d_in[10];
    const void* vWp = d_in[11];
    const void* vWi = d_in[12];
    const void* vWd = d_in[13];
    const void* vWg = d_in[14];
    const void* vbg = d_in[15];
    const void* oW  = d_in[16];
    const void* ob  = d_in[17];

    const size_t SZ = (size_t)M_ROWS * D_MODEL;   // 4,194,304 elems

    // ws layout (base 33 MiB — proven):
    int*   flag = (int*)d_ws;
    float* fws  = (float*)d_ws;
    float* csum = fws + 64;
    float* gq   = csum + 32768;
    float* gk   = gq + 3 * M_ROWS;
    float* gv   = gk + 3 * M_ROWS;
    u16* Ib = (u16*)((char*)d_ws + (1u << 20));
    u16* AO = Ib;                  // alias, disjoint in time
    u16* Qh = Ib + SZ;
    u16* Kh = Qh + SZ;
    u16* Vh = Kh + SZ;

    // bf16 derivative scratch: d_out (8 MiB both wires; dead until gemm1)
    u16* db = (u16*)d_out;

    // bf16 weight cache (proven: r12's 64-VGPR dispatch => ws_size >= 53MiB)
    const size_t NEED_FULL = (size_t)(1u << 20) + 4 * SZ * 2 + ((size_t)10 << 21);
    u16* wb = (ws_size >= NEED_FULL) ? (Vh + SZ) : nullptr;

    detect_kernel<<<1, 64, 0, stream>>>((const u32*)x, flag);
    scan_partial<<<128, 256, 0, stream>>>(x, csum, flag);
    scan_final<<<128, 256, 0, stream>>>(x, csum, Ib, db, flag);
    gates_kernel<<<M_ROWS, 64, 0, stream>>>(x, qWg, qbg, kWg, kbg, vWg, vbg,
                                            gq, gk, gv, flag);

    GemmArgs pa;
    pa.G[0] = gq; pa.G[1] = gk; pa.G[2] = gv;
    pa.C[0] = Qh; pa.C[1] = Kh; pa.C[2] = Vh;
    GemmArgs oa = {};

    if (wb) {
        CvtArgs ca;
        ca.src[0] = qWp; ca.src[1] = qWi; ca.src[2] = qWd;
        ca.src[3] = kWp; ca.src[4] = kWi; ca.src[5] = kWd;
        ca.src[6] = vWp; ca.src[7] = vWi; ca.src[8] = vWd;
        ca.src[9] = oW;
        cvt_w<<<dim3(512, 10), 256, 0, stream>>>(ca, wb, flag);

        for (int z2 = 0; z2 < 3; ++z2)
            for (int s2 = 0; s2 < 3; ++s2)
                pa.W[z2][s2] = wb + ((size_t)(z2 * 3 + s2) << 20);
        oa.W[0][0] = wb + ((size_t)9 << 20);

        mfma_gemm<0, 1><<<dim3(8, 32, 3), 256, 0, stream>>>(
            x, Ib, db, pa, nullptr, nullptr, flag, 3072);
        attn_mfma<<<B_SZ * N_HEADS * (T_SEQ / 64), 256, 0, stream>>>(Qh, Kh, Vh, AO);
        mfma_gemm<1, 1><<<dim3(8, 32, 1), 256, 0, stream>>>(
            nullptr, nullptr, AO, oa, ob, d_out, flag, 1024);
    } else {
        pa.W[0][0] = qWp; pa.W[0][1] = qWi; pa.W[0][2] = qWd;
        pa.W[1][0] = kWp; pa.W[1][1] = kWi; pa.W[1][2] = kWd;
        pa.W[2][0] = vWp; pa.W[2][1] = vWi; pa.W[2][2] = vWd;
        oa.W[0][0] = oW;

        mfma_gemm<0, 0><<<dim3(8, 32, 3), 256, 0, stream>>>(
            x, Ib, db, pa, nullptr, nullptr, flag, 3072);
        attn_mfma<<<B_SZ * N_HEADS * (T_SEQ / 64), 256, 0, stream>>>(Qh, Kh, Vh, AO);
        mfma_gemm<1, 0><<<dim3(8, 32, 1), 256, 0, stream>>>(
            nullptr, nullptr, AO, oa, ob, d_out, flag, 1024);
    }
}